// Round 6
// baseline (382.790 us; speedup 1.0000x reference)
//
#include <hip/hip_runtime.h>

#define TT 1024
#define NH 16
#define DD 128
#define WIN 256
#define SW 288            // stored band width (9 x 32)
#define SCALE 0.08838834764831845f

typedef float f32x4 __attribute__((ext_vector_type(4)));
typedef short s16x8 __attribute__((ext_vector_type(8)));

__device__ __forceinline__ ushort f2bf(float x) {
  union { float f; unsigned u; } v; v.f = x;
  unsigned r = v.u + 0x7FFFu + ((v.u >> 16) & 1u);
  return (ushort)(r >> 16);
}
__device__ __forceinline__ float bf2f(ushort u) {
  union { unsigned u; float f; } v; v.u = ((unsigned)u) << 16; return v.f;
}

// ---------- prep: fp32 [b][t][h][d] -> bf16 [b][h][doct16][t][8] (opt scale) ----------
__global__ __launch_bounds__(256)
void prep_qk(const float* __restrict__ src, ushort* __restrict__ dst, float scale)
{
  const int tid = threadIdx.x;
  const int bidx = blockIdx.x;                 // 512 = b2*h16*tt16
  const int tt = bidx & 15, h = (bidx >> 4) & 15, b = bidx >> 8;
  const int t0 = tt * 64;
  __shared__ float sQ[64 * 132];
#pragma unroll
  for (int it = 0; it < 8; ++it) {
    int idx = tid + it * 256;                  // 2048 float4
    int r = idx >> 5, cg = idx & 31;
    float4 v = *(const float4*)(src + (((long long)(b * TT + t0 + r)) * NH + h) * DD + cg * 4);
    *(float4*)(&sQ[r * 132 + cg * 4]) = v;
  }
  __syncthreads();
#pragma unroll
  for (int it = 0; it < 4; ++it) {
    int idx = tid + it * 256;                  // 1024 items
    int t = idx & 63, doct = idx >> 6;
    union { ushort u[8]; uint4 v; } pk;
#pragma unroll
    for (int e = 0; e < 8; ++e)
      pk.u[e] = f2bf(sQ[t * 132 + doct * 8 + e] * scale);
    *(uint4*)(dst + ((((long long)(b * NH + h)) * 16 + doct) * TT + t0 + t) * 8) = pk.v;
  }
}

// ---------- prep: v fp32 [b][s][h][d] -> bf16 [b][h][soct128][d][8] ----------
__global__ __launch_bounds__(256)
void prep_v(const float* __restrict__ v, ushort* __restrict__ v8)
{
  const int tid = threadIdx.x;
  const int bidx = blockIdx.x;                 // 512 = b2*h16*st16
  const int st = bidx & 15, h = (bidx >> 4) & 15, b = bidx >> 8;
  const int s0 = st * 64;
  __shared__ float sV[64 * 132];
#pragma unroll
  for (int it = 0; it < 8; ++it) {
    int idx = tid + it * 256;
    int r = idx >> 5, cg = idx & 31;
    float4 x = *(const float4*)(v + (((long long)(b * TT + s0 + r)) * NH + h) * DD + cg * 4);
    *(float4*)(&sV[r * 132 + cg * 4]) = x;
  }
  __syncthreads();
#pragma unroll
  for (int it = 0; it < 4; ++it) {
    int idx = tid + it * 256;                  // 1024 items: (so8 x d128)
    int d = idx & 127, so = idx >> 7;
    union { ushort u[8]; uint4 v; } pk;
#pragma unroll
    for (int e = 0; e < 8; ++e)
      pk.u[e] = f2bf(sV[(so * 8 + e) * 132 + d]);
    *(uint4*)(v8 + ((((long long)(b * NH + h)) * 128 + st * 8 + so) * DD + d) * 8) = pk.v;
  }
}

// ---------- prep: kw1/kw2/kdd -> lane-coalesced transposed layouts ----------
// kw1T: [(pass*2+b)*16+m][s][2] fp32 ; kwcT: [(pass*2+b)*16+n][s][4] = {kw2_0,kw2_1,kdd,0}
__global__ __launch_bounds__(256)
void prep_kw(const float* __restrict__ kw1_pre, const float* __restrict__ kw2_pre,
             const float* __restrict__ kdd_pre,
             const float* __restrict__ kw1_post, const float* __restrict__ kw2_post,
             const float* __restrict__ kdd_post,
             float* __restrict__ kw1T, float* __restrict__ kwcT)
{
  const int bidx = blockIdx.x;                 // 32 = pass2 * b2 * 8chunk
  const int ch = bidx & 7, b = (bidx >> 3) & 1, pass = bidx >> 4;
  const int s = ch * 128 + (threadIdx.x & 127);
  const int half = threadIdx.x >> 7;
  const long long bs = (long long)b * TT + s;
  const long long obase = ((long long)(pass * 2 + b) * 16) * TT;
  if (half == 0) {
    const float* src = pass ? kw1_post : kw1_pre;
    float w[32];
#pragma unroll
    for (int i = 0; i < 8; ++i) ((float4*)w)[i] = ((const float4*)(src + bs * 32))[i];
#pragma unroll
    for (int m = 0; m < 16; ++m)
      *(float2*)(kw1T + (obase + (long long)m * TT + s) * 2) = make_float2(w[2*m], w[2*m+1]);
  } else {
    const float* s2 = pass ? kw2_post : kw2_pre;
    const float* sd = pass ? kdd_post : kdd_pre;
    float w[32], d[16];
#pragma unroll
    for (int i = 0; i < 8; ++i) ((float4*)w)[i] = ((const float4*)(s2 + bs * 32))[i];
#pragma unroll
    for (int i = 0; i < 4; ++i) ((float4*)d)[i] = ((const float4*)(sd + bs * 16))[i];
#pragma unroll
    for (int n = 0; n < 16; ++n)
      *(float4*)(kwcT + (obase + (long long)n * TT + s) * 4) = make_float4(w[2*n], w[2*n+1], d[n], 0.f);
  }
}

// ---------- KA: QK^T band GEMM per (b,h,32-t tile) -> S bf16 rows ----------
__global__ __launch_bounds__(256, 4)
void ka_qk(const ushort* __restrict__ qb8, const ushort* __restrict__ kb8,
           ushort* __restrict__ S)
{
  const int tid = threadIdx.x;
  const int raw = blockIdx.x;                  // 1024 = 8*128
  const int job = (raw & 7) * 128 + (raw >> 3);
  const int b = job >> 9, h = (job >> 5) & 15, tt = job & 31;
  const int t0 = tt * 32;
  const int s0 = (t0 >= WIN) ? t0 - WIN : 0;
  const int lane = tid & 63, wv = tid >> 6;

  __shared__ float strip[16 * 300];

  const ushort* qbase = qb8 + ((long long)(b * NH + h)) * 16 * (TT * 8);
  const ushort* kbase = kb8 + ((long long)(b * NH + h)) * 16 * (TT * 8);

  for (int rt = 0; rt < 2; ++rt) {
    const int tlo = t0 + rt * 16;
    s16x8 qa[4];
    {
      const int trow = tlo + (lane & 15);
      const int ko = lane >> 4;
#pragma unroll
      for (int kk = 0; kk < 4; ++kk)
        qa[kk] = *(const s16x8*)(qbase + ((long long)(kk * 4 + ko)) * (TT * 8) + trow * 8);
    }
    int cl0 = tlo - (WIN - 1) - s0; if (cl0 < 0) cl0 = 0;
    const int chi = tlo + 15 - s0;
    const int stb = cl0 >> 4;
    const int nst = (chi >> 4) - stb + 1;
    for (int sti = wv; sti < nst; sti += 4) {
      const int cst = (stb + sti) * 16;
      const int scol = s0 + cst + (lane & 15);
      const int ko = lane >> 4;
      f32x4 acc = {0.f, 0.f, 0.f, 0.f};
#pragma unroll
      for (int kk = 0; kk < 4; ++kk) {
        s16x8 kb = *(const s16x8*)(kbase + ((long long)(kk * 4 + ko)) * (TT * 8) + scol * 8);
        acc = __builtin_amdgcn_mfma_f32_16x16x32_bf16(qa[kk], kb, acc, 0, 0, 0);
      }
      const int r0 = (lane >> 4) * 4;
#pragma unroll
      for (int j = 0; j < 4; ++j)
        strip[(r0 + j) * 300 + cst + (lane & 15)] = acc[j];
    }
    __syncthreads();
    const long long srow0 = (((long long)(b * NH + h)) * TT + tlo) * SW;
#pragma unroll
    for (int it = 0; it < 3; ++it) {
      int idx = tid + it * 256;
      if (idx < 16 * 36) {
        int r = idx / 36, sg = idx % 36;
        union { ushort u[8]; uint4 v; } pk;
#pragma unroll
        for (int e = 0; e < 8; ++e)
          pk.u[e] = f2bf(strip[r * 300 + sg * 8 + e]);
        *(uint4*)(S + srow0 + (long long)r * SW + sg * 8) = pk.v;
      }
    }
    __syncthreads();
  }
}

// ---------- KB: register-resident proj+softmax, per (b, t-pair) ----------
__global__ __launch_bounds__(192, 3)
void kb_proj(const float* __restrict__ w_pre, const float* __restrict__ w_post,
             const float* __restrict__ qw1_pre, const float* __restrict__ qw2_pre,
             const float* __restrict__ qdd_pre,
             const float* __restrict__ qw1_post, const float* __restrict__ qw2_post,
             const float* __restrict__ qdd_post,
             const float* __restrict__ kw1T, const float* __restrict__ kwcT,
             ushort* __restrict__ S)
{
  const int tid = threadIdx.x;
  const int raw = blockIdx.x;                  // 1024 = 8*128
  const int job = (raw & 7) * 128 + (raw >> 3);
  const int b = job >> 9, tp = job & 511;
  const int t0 = tp * 2;
  const int tj = (tid >= 96) ? 1 : 0;
  const int c  = tid - tj * 96;
  const int t  = t0 + tj;
  const int tb32 = t & ~31;
  const int s0 = (tb32 >= WIN) ? tb32 - WIN : 0;

  __shared__ float sMq[2][2][256];             // [pass][tj][m*16+n]
  __shared__ float sZp[2][3][16];

  // ---- build Mq = I + W + qw1*qw2^T + diag(qdd), both passes & t's ----
#pragma unroll
  for (int ii = 0; ii < 6; ++ii) {
    int e = ii * 192 + tid;
    if (e < 1024) {
      int n = e & 15, m = (e >> 4) & 15, tq = (e >> 8) & 1, pp = e >> 9;
      const float* W   = pp ? w_post   : w_pre;
      const float* QW1 = pp ? qw1_post : qw1_pre;
      const float* QW2 = pp ? qw2_post : qw2_pre;
      const float* QDD = pp ? qdd_post : qdd_pre;
      long long btq = (long long)b * TT + t0 + tq;
      float val = W[m * 16 + n]
                + QW1[btq * 32 + 2 * m] * QW2[btq * 32 + 2 * n]
                + QW1[btq * 32 + 2 * m + 1] * QW2[btq * 32 + 2 * n + 1];
      if (m == n) val += 1.0f + QDD[btq * 16 + n];
      sMq[pp][tq][m * 16 + n] = val;
    }
  }
  __syncthreads();

  const int cc0 = c, cc1 = c + 96, cc2 = c + 192;
  const int sg0 = s0 + cc0, sg1 = s0 + cc1, sg2 = s0 + cc2;

  // ---- load logits columns (each thread owns 3 columns end-to-end) ----
  float inp[3][16];
#pragma unroll
  for (int m = 0; m < 16; ++m) {
    const ushort* Sp = S + (((long long)(b * NH + m)) * TT + t) * SW;
    inp[0][m] = bf2f(Sp[cc0]);
    inp[1][m] = bf2f(Sp[cc1]);
    inp[2][m] = bf2f(Sp[cc2]);
  }

  float eb[3][16];
  // ================= PASS 1: pre-proj + mask + exp =================
  {
    const long long kwb = ((long long)b * 16) * TT;
    float hk00=0.f,hk01=0.f,hk10=0.f,hk11=0.f,hk20=0.f,hk21=0.f;
    float rt[3][16];
#pragma unroll
    for (int j = 0; j < 3; ++j)
#pragma unroll
      for (int n = 0; n < 16; ++n) rt[j][n] = 0.f;
#pragma unroll
    for (int m = 0; m < 16; ++m) {
      const float* k1 = kw1T + (kwb + (long long)m * TT) * 2;
      float2 wa = *(const float2*)(k1 + sg0 * 2);
      float2 wb = *(const float2*)(k1 + sg1 * 2);
      float2 wc = *(const float2*)(k1 + sg2 * 2);
      hk00 = fmaf(inp[0][m], wa.x, hk00); hk01 = fmaf(inp[0][m], wa.y, hk01);
      hk10 = fmaf(inp[1][m], wb.x, hk10); hk11 = fmaf(inp[1][m], wb.y, hk11);
      hk20 = fmaf(inp[2][m], wc.x, hk20); hk21 = fmaf(inp[2][m], wc.y, hk21);
      const float* MQ = &sMq[0][tj][m * 16];
#pragma unroll
      for (int nq = 0; nq < 4; ++nq) {
        f32x4 w = *(const f32x4*)(MQ + nq * 4);
#pragma unroll
        for (int l = 0; l < 4; ++l) {
          rt[0][nq*4+l] = fmaf(inp[0][m], w[l], rt[0][nq*4+l]);
          rt[1][nq*4+l] = fmaf(inp[1][m], w[l], rt[1][nq*4+l]);
          rt[2][nq*4+l] = fmaf(inp[2][m], w[l], rt[2][nq*4+l]);
        }
      }
    }
    const bool v0 = (sg0 <= t) && (sg0 + WIN > t);
    const bool v1 = (sg1 <= t) && (sg1 + WIN > t);
    const bool v2 = (sg2 <= t) && (sg2 + WIN > t);
#pragma unroll
    for (int n = 0; n < 16; ++n) {
      const float* kc = kwcT + (kwb + (long long)n * TT) * 4;
      float4 wA = *(const float4*)(kc + sg0 * 4);
      float4 wB = *(const float4*)(kc + sg1 * 4);
      float4 wC = *(const float4*)(kc + sg2 * 4);
      float x0 = rt[0][n] + hk00 * wA.x + hk01 * wA.y + inp[0][n] * wA.z;
      float x1 = rt[1][n] + hk10 * wB.x + hk11 * wB.y + inp[1][n] * wB.z;
      float x2 = rt[2][n] + hk20 * wC.x + hk21 * wC.y + inp[2][n] * wC.z;
      eb[0][n] = v0 ? __expf(x0) : 0.f;
      eb[1][n] = v1 ? __expf(x1) : 0.f;
      eb[2][n] = v2 ? __expf(x2) : 0.f;
    }
  }

  // ---- Z reduction (32-lane groups share tj; 3 groups per tj) ----
  float rz[16];
  {
    const int lane = tid & 63;
    const int grp = tid >> 5;                  // 0..5; 0-2 -> tj0, 3-5 -> tj1
#pragma unroll
    for (int n = 0; n < 16; ++n) {
      float z = eb[0][n] + eb[1][n] + eb[2][n];
      z += __shfl_xor(z, 1); z += __shfl_xor(z, 2); z += __shfl_xor(z, 4);
      z += __shfl_xor(z, 8); z += __shfl_xor(z, 16);
      if ((lane & 31) == 0) sZp[grp >= 3][grp % 3][n] = z;
    }
    __syncthreads();
#pragma unroll
    for (int n = 0; n < 16; ++n)
      rz[n] = 1.0f / (sZp[tj][0][n] + sZp[tj][1][n] + sZp[tj][2][n]);
  }

  // ================= PASS 2: normalize + post-proj -> S =================
  {
    const long long kwb = ((long long)(2 + b) * 16) * TT;
    float hk00=0.f,hk01=0.f,hk10=0.f,hk11=0.f,hk20=0.f,hk21=0.f;
    float rt[3][16];
#pragma unroll
    for (int j = 0; j < 3; ++j)
#pragma unroll
      for (int n = 0; n < 16; ++n) rt[j][n] = 0.f;
#pragma unroll
    for (int m = 0; m < 16; ++m) {
      float p0 = eb[0][m] * rz[m], p1 = eb[1][m] * rz[m], p2 = eb[2][m] * rz[m];
      const float* k1 = kw1T + (kwb + (long long)m * TT) * 2;
      float2 wa = *(const float2*)(k1 + sg0 * 2);
      float2 wb = *(const float2*)(k1 + sg1 * 2);
      float2 wc = *(const float2*)(k1 + sg2 * 2);
      hk00 = fmaf(p0, wa.x, hk00); hk01 = fmaf(p0, wa.y, hk01);
      hk10 = fmaf(p1, wb.x, hk10); hk11 = fmaf(p1, wb.y, hk11);
      hk20 = fmaf(p2, wc.x, hk20); hk21 = fmaf(p2, wc.y, hk21);
      const float* MQ = &sMq[1][tj][m * 16];
#pragma unroll
      for (int nq = 0; nq < 4; ++nq) {
        f32x4 w = *(const f32x4*)(MQ + nq * 4);
#pragma unroll
        for (int l = 0; l < 4; ++l) {
          rt[0][nq*4+l] = fmaf(p0, w[l], rt[0][nq*4+l]);
          rt[1][nq*4+l] = fmaf(p1, w[l], rt[1][nq*4+l]);
          rt[2][nq*4+l] = fmaf(p2, w[l], rt[2][nq*4+l]);
        }
      }
    }
#pragma unroll
    for (int n = 0; n < 16; ++n) {
      const float* kc = kwcT + (kwb + (long long)n * TT) * 4;
      float4 wA = *(const float4*)(kc + sg0 * 4);
      float4 wB = *(const float4*)(kc + sg1 * 4);
      float4 wC = *(const float4*)(kc + sg2 * 4);
      ushort* So = S + (((long long)(b * NH + n)) * TT + t) * SW;
      float pn0 = eb[0][n] * rz[n], pn1 = eb[1][n] * rz[n], pn2 = eb[2][n] * rz[n];
      So[cc0] = f2bf(rt[0][n] + hk00 * wA.x + hk01 * wA.y + pn0 * wA.z);
      So[cc1] = f2bf(rt[1][n] + hk10 * wB.x + hk11 * wB.y + pn1 * wB.z);
      So[cc2] = f2bf(rt[2][n] + hk20 * wC.x + hk21 * wC.y + pn2 * wC.z);
    }
  }
}

// ---------- KC: PV band GEMM per (b,h,32-t tile) ----------
__global__ __launch_bounds__(256, 4)
void kc_pv(const ushort* __restrict__ S, const ushort* __restrict__ v8,
           float* __restrict__ out)
{
  const int tid = threadIdx.x;
  const int raw = blockIdx.x;                  // 1024 = 8*128
  const int job = (raw & 7) * 128 + (raw >> 3);
  const int b = job >> 9, h = (job >> 5) & 15, tt = job & 31;
  const int t0 = tt * 32;
  const int s0 = (t0 >= WIN) ? t0 - WIN : 0;
  const int lane = tid & 63, wv = tid >> 6;

  __shared__ ushort sPt[32 * 296];

  const long long prow0 = (((long long)(b * NH + h)) * TT + t0) * SW;
#pragma unroll
  for (int it = 0; it < 5; ++it) {
    int idx = tid + it * 256;
    if (idx < 32 * 36) {
      int r = idx / 36, sg = idx % 36;
      uint4 v = *(const uint4*)(S + prow0 + (long long)r * SW + sg * 8);
      *(uint4*)(&sPt[r * 296 + sg * 8]) = v;
    }
  }
  __syncthreads();

  const ushort* vbase = v8 + ((long long)(b * NH + h)) * (128 * DD * 8)
                           + ((long long)(s0 >> 3)) * (DD * 8);
  const int dcol = lane & 15, soct = lane >> 4;
  const int dt0 = wv * 2;
  f32x4 acc[2][2];
#pragma unroll
  for (int rt = 0; rt < 2; ++rt)
#pragma unroll
    for (int dd = 0; dd < 2; ++dd) acc[rt][dd] = (f32x4){0.f, 0.f, 0.f, 0.f};

#pragma unroll
  for (int ks = 0; ks < 9; ++ks) {
    s16x8 a0 = *(const s16x8*)(&sPt[(dcol) * 296 + ks * 32 + soct * 8]);
    s16x8 a1 = *(const s16x8*)(&sPt[(16 + dcol) * 296 + ks * 32 + soct * 8]);
#pragma unroll
    for (int dd = 0; dd < 2; ++dd) {
      s16x8 vb = *(const s16x8*)(vbase + (((long long)(ks * 4 + soct)) * DD + (dt0 + dd) * 16 + dcol) * 8);
      acc[0][dd] = __builtin_amdgcn_mfma_f32_16x16x32_bf16(a0, vb, acc[0][dd], 0, 0, 0);
      acc[1][dd] = __builtin_amdgcn_mfma_f32_16x16x32_bf16(a1, vb, acc[1][dd], 0, 0, 0);
    }
  }
  const int r0 = (lane >> 4) * 4;
#pragma unroll
  for (int rt = 0; rt < 2; ++rt)
#pragma unroll
    for (int dd = 0; dd < 2; ++dd)
#pragma unroll
      for (int j = 0; j < 4; ++j) {
        int trow = t0 + rt * 16 + r0 + j;
        out[(((long long)(b * TT + trow)) * NH + h) * DD + (dt0 + dd) * 16 + dcol] = acc[rt][dd][j];
      }
}

extern "C" void kernel_launch(void* const* d_in, const int* in_sizes, int n_in,
                              void* d_out, int out_size, void* d_ws, size_t ws_size,
                              hipStream_t stream) {
  const float* q        = (const float*)d_in[0];
  const float* k        = (const float*)d_in[1];
  const float* v        = (const float*)d_in[2];
  const float* w_pre    = (const float*)d_in[3];
  const float* w_post   = (const float*)d_in[4];
  const float* qw1_pre  = (const float*)d_in[5];
  const float* qw2_pre  = (const float*)d_in[6];
  const float* kw1_pre  = (const float*)d_in[7];
  const float* kw2_pre  = (const float*)d_in[8];
  const float* qw1_post = (const float*)d_in[9];
  const float* qw2_post = (const float*)d_in[10];
  const float* kw1_post = (const float*)d_in[11];
  const float* kw2_post = (const float*)d_in[12];
  const float* qdd_pre  = (const float*)d_in[13];
  const float* kdd_pre  = (const float*)d_in[14];
  const float* qdd_post = (const float*)d_in[15];
  const float* kdd_post = (const float*)d_in[16];
  float* out = (float*)d_out;

  // ws: qb8 8MB | kb8 8MB | v8 8MB | S 18MB | kw1T 512KB | kwcT 1MB
  ushort* qb8  = (ushort*)d_ws;
  ushort* kb8  = (ushort*)((char*)d_ws + 8388608ll);
  ushort* v8   = (ushort*)((char*)d_ws + 16777216ll);
  ushort* S    = (ushort*)((char*)d_ws + 25165824ll);
  float*  kw1T = (float*) ((char*)d_ws + 44040192ll);
  float*  kwcT = (float*) ((char*)d_ws + 44564480ll);

  prep_qk<<<512, 256, 0, stream>>>(q, qb8, SCALE);
  prep_qk<<<512, 256, 0, stream>>>(k, kb8, 1.0f);
  prep_v <<<512, 256, 0, stream>>>(v, v8);
  prep_kw<<<32, 256, 0, stream>>>(kw1_pre, kw2_pre, kdd_pre,
                                  kw1_post, kw2_post, kdd_post, kw1T, kwcT);
  ka_qk  <<<1024, 256, 0, stream>>>(qb8, kb8, S);
  kb_proj<<<1024, 192, 0, stream>>>(w_pre, w_post,
                                    qw1_pre, qw2_pre, qdd_pre,
                                    qw1_post, qw2_post, qdd_post,
                                    kw1T, kwcT, S);
  kc_pv  <<<1024, 256, 0, stream>>>(S, v8, out);
}

// Round 7
// 88.464 us; speedup vs baseline: 4.3271x; 4.3271x over previous
//
#include <hip/hip_runtime.h>

#define TT 1024
#define NH 16
#define DD 128
#define WIN 256
#define SW 288            // stored band width (9 x 32)
#define KWR 80            // packed kw rows: 32 kw1 + 32 kw2 + 16 kdd
#define SCALE 0.08838834764831845f

typedef float f32x4 __attribute__((ext_vector_type(4)));
typedef short s16x8 __attribute__((ext_vector_type(8)));

__device__ __forceinline__ ushort f2bf(float x) {
  union { float f; unsigned u; } v; v.f = x;
  unsigned r = v.u + 0x7FFFu + ((v.u >> 16) & 1u);
  return (ushort)(r >> 16);
}
__device__ __forceinline__ float bf2f(ushort u) {
  union { unsigned u; float f; } v; v.u = ((unsigned)u) << 16; return v.f;
}

// ---------- prep: fp32 [b][t][h][d] -> bf16 [b][h][doct16][t][8] (opt scale) ----------
__global__ __launch_bounds__(256)
void prep_qk(const float* __restrict__ src, ushort* __restrict__ dst, float scale)
{
  const int tid = threadIdx.x;
  const int bidx = blockIdx.x;                 // 512 = b2*h16*tt16
  const int tt = bidx & 15, h = (bidx >> 4) & 15, b = bidx >> 8;
  const int t0 = tt * 64;
  __shared__ float sQ[64 * 132];
#pragma unroll
  for (int it = 0; it < 8; ++it) {
    int idx = tid + it * 256;                  // 2048 float4
    int r = idx >> 5, cg = idx & 31;
    float4 v = *(const float4*)(src + (((long long)(b * TT + t0 + r)) * NH + h) * DD + cg * 4);
    *(float4*)(&sQ[r * 132 + cg * 4]) = v;
  }
  __syncthreads();
#pragma unroll
  for (int it = 0; it < 4; ++it) {
    int idx = tid + it * 256;                  // 1024 items
    int t = idx & 63, doct = idx >> 6;
    union { ushort u[8]; uint4 v; } pk;
#pragma unroll
    for (int e = 0; e < 8; ++e)
      pk.u[e] = f2bf(sQ[t * 132 + doct * 8 + e] * scale);
    *(uint4*)(dst + ((((long long)(b * NH + h)) * 16 + doct) * TT + t0 + t) * 8) = pk.v;
  }
}

// ---------- prep: v fp32 [b][s][h][d] -> bf16 [b][h][soct128][d][8] ----------
__global__ __launch_bounds__(256)
void prep_v(const float* __restrict__ v, ushort* __restrict__ v8)
{
  const int tid = threadIdx.x;
  const int bidx = blockIdx.x;                 // 512 = b2*h16*st16
  const int st = bidx & 15, h = (bidx >> 4) & 15, b = bidx >> 8;
  const int s0 = st * 64;
  __shared__ float sV[64 * 132];
#pragma unroll
  for (int it = 0; it < 8; ++it) {
    int idx = tid + it * 256;
    int r = idx >> 5, cg = idx & 31;
    float4 x = *(const float4*)(v + (((long long)(b * TT + s0 + r)) * NH + h) * DD + cg * 4);
    *(float4*)(&sV[r * 132 + cg * 4]) = x;
  }
  __syncthreads();
#pragma unroll
  for (int it = 0; it < 4; ++it) {
    int idx = tid + it * 256;                  // 1024 items: (so8 x d128)
    int d = idx & 127, so = idx >> 7;
    union { ushort u[8]; uint4 v; } pk;
#pragma unroll
    for (int e = 0; e < 8; ++e)
      pk.u[e] = f2bf(sV[(so * 8 + e) * 132 + d]);
    *(uint4*)(v8 + ((((long long)(b * NH + h)) * 128 + st * 8 + so) * DD + d) * 8) = pk.v;
  }
}

// ---------- prep: pack kw1/kw2/kdd -> kwsT[(pass*2+b)*80 + j][s] bf16 ----------
// j: 0..31 = kw1[m][i] (2m+i), 32..63 = kw2[n][i], 64..79 = kdd[n]
__global__ __launch_bounds__(256)
void prep_kws(const float* __restrict__ kw1_pre, const float* __restrict__ kw2_pre,
              const float* __restrict__ kdd_pre,
              const float* __restrict__ kw1_post, const float* __restrict__ kw2_post,
              const float* __restrict__ kdd_post,
              ushort* __restrict__ kwsT)
{
  const int bidx = blockIdx.x;                 // 64 = pass2 * b2 * 16 s-chunks(64)
  const int sch = bidx & 15, b = (bidx >> 4) & 1, pass = bidx >> 5;
  const int s0b = sch * 64;
  const float* KW1 = pass ? kw1_post : kw1_pre;
  const float* KW2 = pass ? kw2_post : kw2_pre;
  const float* KDD = pass ? kdd_post : kdd_pre;
  __shared__ float sKW[64][84];
  const int tid = threadIdx.x;
#pragma unroll
  for (int k = 0; k < 5; ++k) {
    int idx = tid + k * 256;                   // 1280 = 64 s * 20 f4
    int s = idx / 20, q4 = idx % 20;
    long long bs = (long long)b * TT + s0b + s;
    float4 v; int dst;
    if (q4 < 8)       { v = ((const float4*)(KW1 + bs * 32))[q4];      dst = q4 * 4; }
    else if (q4 < 16) { v = ((const float4*)(KW2 + bs * 32))[q4 - 8];  dst = 32 + (q4 - 8) * 4; }
    else              { v = ((const float4*)(KDD + bs * 16))[q4 - 16]; dst = 64 + (q4 - 16) * 4; }
    *(float4*)(&sKW[s][dst]) = v;
  }
  __syncthreads();
#pragma unroll
  for (int k = 0; k < 3; ++k) {
    int idx = tid + k * 256;                   // 640 = 80 j * 8 so8
    if (idx < 640) {
      int j = idx >> 3, so8 = idx & 7;
      union { ushort u[8]; uint4 v; } pk;
#pragma unroll
      for (int e = 0; e < 8; ++e) pk.u[e] = f2bf(sKW[so8 * 8 + e][j]);
      *(uint4*)(kwsT + ((long long)((pass * 2 + b) * KWR + j)) * TT + s0b + so8 * 8) = pk.v;
    }
  }
}

// ---------- KA: QK^T band GEMM per (b,h,32-t tile) -> S bf16 rows ----------
__global__ __launch_bounds__(256, 4)
void ka_qk(const ushort* __restrict__ qb8, const ushort* __restrict__ kb8,
           ushort* __restrict__ S)
{
  const int tid = threadIdx.x;
  const int raw = blockIdx.x;                  // 1024 = 8*128
  const int job = (raw & 7) * 128 + (raw >> 3);
  const int b = job >> 9, h = (job >> 5) & 15, tt = job & 31;
  const int t0 = tt * 32;
  const int s0 = (t0 >= WIN) ? t0 - WIN : 0;
  const int lane = tid & 63, wv = tid >> 6;

  __shared__ float strip[16 * 300];

  const ushort* qbase = qb8 + ((long long)(b * NH + h)) * 16 * (TT * 8);
  const ushort* kbase = kb8 + ((long long)(b * NH + h)) * 16 * (TT * 8);

  for (int rt = 0; rt < 2; ++rt) {
    const int tlo = t0 + rt * 16;
    s16x8 qa[4];
    {
      const int trow = tlo + (lane & 15);
      const int ko = lane >> 4;
#pragma unroll
      for (int kk = 0; kk < 4; ++kk)
        qa[kk] = *(const s16x8*)(qbase + ((long long)(kk * 4 + ko)) * (TT * 8) + trow * 8);
    }
    int cl0 = tlo - (WIN - 1) - s0; if (cl0 < 0) cl0 = 0;
    const int chi = tlo + 15 - s0;
    const int stb = cl0 >> 4;
    const int nst = (chi >> 4) - stb + 1;
    for (int sti = wv; sti < nst; sti += 4) {
      const int cst = (stb + sti) * 16;
      const int scol = s0 + cst + (lane & 15);
      const int ko = lane >> 4;
      f32x4 acc = {0.f, 0.f, 0.f, 0.f};
#pragma unroll
      for (int kk = 0; kk < 4; ++kk) {
        s16x8 kb = *(const s16x8*)(kbase + ((long long)(kk * 4 + ko)) * (TT * 8) + scol * 8);
        acc = __builtin_amdgcn_mfma_f32_16x16x32_bf16(qa[kk], kb, acc, 0, 0, 0);
      }
      const int r0 = (lane >> 4) * 4;
#pragma unroll
      for (int j = 0; j < 4; ++j)
        strip[(r0 + j) * 300 + cst + (lane & 15)] = acc[j];
    }
    __syncthreads();
    const long long srow0 = (((long long)(b * NH + h)) * TT + tlo) * SW;
#pragma unroll
    for (int it = 0; it < 3; ++it) {
      int idx = tid + it * 256;
      if (idx < 16 * 36) {
        int r = idx / 36, sg = idx % 36;
        union { ushort u[8]; uint4 v; } pk;
#pragma unroll
        for (int e = 0; e < 8; ++e)
          pk.u[e] = f2bf(strip[r * 300 + sg * 8 + e]);
        *(uint4*)(S + srow0 + (long long)r * SW + sg * 8) = pk.v;
      }
    }
    __syncthreads();
  }
}

// ---------- KB: LDS-staged dbuf proj+softmax, per (b, 2 t) ----------
__global__ __launch_bounds__(192, 3)
void kb_proj(const float* __restrict__ w_pre, const float* __restrict__ w_post,
             const float* __restrict__ qw1_pre, const float* __restrict__ qw2_pre,
             const float* __restrict__ qdd_pre,
             const float* __restrict__ qw1_post, const float* __restrict__ qw2_post,
             const float* __restrict__ qdd_post,
             const ushort* __restrict__ kwsT, ushort* __restrict__ S)
{
  const int tid = threadIdx.x;
  const int raw = blockIdx.x;                  // 1024 = 8*128
  const int job = (raw & 7) * 128 + (raw >> 3);
  const int b = job >> 9, tp = job & 511;
  const int t0 = tp * 2;
  const int t32 = t0 & ~31;
  const int s0 = (t32 >= WIN) ? t32 - WIN : 0;
  const int tj = (tid >= 96) ? 1 : 0;
  const int c  = tid - tj * 96;                // band col within chunk, 0..95
  const int t  = t0 + tj;

  __shared__ ushort skw[2][KWR][96];
  __shared__ float  sMq[2][256];               // [t of pair][m*16+n], one pass at a time
  __shared__ float  sZp[6][16];

  const ushort* kwb1 = kwsT + ((long long)(b * KWR)) * TT;
  const ushort* kwb2 = kwsT + ((long long)((2 + b) * KWR)) * TT;
  const int jb = tid / 12, so8 = tid % 12;     // staging decomposition (192 = 16*12)
  ushort* Sbase = S + (((long long)(b * NH)) * TT + t) * SW;

#define BUILD_MQ(W, QW1, QW2, QDD)                                           \
  {                                                                           \
    _Pragma("unroll")                                                         \
    for (int ii = 0; ii < 3; ++ii) {                                          \
      int e = ii * 192 + tid;                                                 \
      if (e < 512) {                                                          \
        int n = e & 15, m = (e >> 4) & 15, tq = e >> 8;                       \
        long long btq = (long long)b * TT + t0 + tq;                          \
        float val = (W)[m * 16 + n]                                           \
                  + (QW1)[btq * 32 + 2 * m] * (QW2)[btq * 32 + 2 * n]         \
                  + (QW1)[btq * 32 + 2 * m + 1] * (QW2)[btq * 32 + 2 * n + 1];\
        if (m == n) val += 1.0f + (QDD)[btq * 16 + n];                        \
        sMq[tq][m * 16 + n] = val;                                            \
      }                                                                       \
    }                                                                         \
  }

#define GLOAD(BASE, CH)                                                       \
  {                                                                           \
    _Pragma("unroll")                                                         \
    for (int k = 0; k < 5; ++k)                                               \
      rg[k] = *(const uint4*)((BASE) + ((long long)(jb + k * 16)) * TT        \
                              + s0 + (CH) * 96 + so8 * 8);                    \
  }
#define DSWR(BUF)                                                             \
  {                                                                           \
    _Pragma("unroll")                                                         \
    for (int k = 0; k < 5; ++k)                                               \
      *(uint4*)(&skw[BUF][jb + k * 16][so8 * 8]) = rg[k];                     \
  }

  BUILD_MQ(w_pre, qw1_pre, qw2_pre, qdd_pre);
  uint4 rg[5];
  GLOAD(kwb1, 0);
  DSWR(0);
  __syncthreads();

  float zpart[16];
#pragma unroll
  for (int n = 0; n < 16; ++n) zpart[n] = 0.f;

  // ================= PASS 1: pre-proj + mask + exp -> S =================
#pragma unroll
  for (int ch = 0; ch < 3; ++ch) {
    if (ch < 2) { GLOAD(kwb1, ch + 1); } else { GLOAD(kwb2, 0); }
    const int buf = ch & 1;
    const int cc = ch * 96 + c;
    const int sg = s0 + cc;
    float inp[16];
#pragma unroll
    for (int m = 0; m < 16; ++m)
      inp[m] = bf2f(Sbase[(long long)m * (TT * SW) + cc]);
    float hk0 = 0.f, hk1 = 0.f;
    float rt[16];
#pragma unroll
    for (int n = 0; n < 16; ++n) rt[n] = 0.f;
#pragma unroll
    for (int m = 0; m < 16; ++m) {
      hk0 = fmaf(inp[m], bf2f(skw[buf][2 * m][c]), hk0);
      hk1 = fmaf(inp[m], bf2f(skw[buf][2 * m + 1][c]), hk1);
      const float* MQ = &sMq[tj][m * 16];
#pragma unroll
      for (int n4 = 0; n4 < 4; ++n4) {
        f32x4 w = *(const f32x4*)(MQ + n4 * 4);
        rt[n4*4+0] = fmaf(inp[m], w[0], rt[n4*4+0]);
        rt[n4*4+1] = fmaf(inp[m], w[1], rt[n4*4+1]);
        rt[n4*4+2] = fmaf(inp[m], w[2], rt[n4*4+2]);
        rt[n4*4+3] = fmaf(inp[m], w[3], rt[n4*4+3]);
      }
    }
    const bool valid = (sg <= t) && (sg + WIN > t);
#pragma unroll
    for (int n = 0; n < 16; ++n) {
      float x = rt[n] + hk0 * bf2f(skw[buf][32 + 2 * n][c])
              + hk1 * bf2f(skw[buf][33 + 2 * n][c])
              + inp[n] * bf2f(skw[buf][64 + n][c]);
      float e = valid ? __expf(x) : 0.f;
      zpart[n] += e;
      Sbase[(long long)n * (TT * SW) + cc] = f2bf(e);
    }
    DSWR((ch + 1) & 1);
    __syncthreads();
  }

  // ---- Z reduce: 32-lane groups (each group one t), then combine 3 groups ----
  {
    const int grp = tid >> 5;
#pragma unroll
    for (int n = 0; n < 16; ++n) {
      float z = zpart[n];
      z += __shfl_xor(z, 1);  z += __shfl_xor(z, 2);  z += __shfl_xor(z, 4);
      z += __shfl_xor(z, 8);  z += __shfl_xor(z, 16);
      if ((tid & 31) == 0) sZp[grp][n] = z;
    }
  }
  BUILD_MQ(w_post, qw1_post, qw2_post, qdd_post);
  __syncthreads();
  float rz[16];
#pragma unroll
  for (int m = 0; m < 16; ++m)
    rz[m] = 1.0f / (sZp[tj * 3][m] + sZp[tj * 3 + 1][m] + sZp[tj * 3 + 2][m]);

  // ================= PASS 2: normalize + post-proj -> S =================
#pragma unroll
  for (int ch = 0; ch < 3; ++ch) {
    if (ch < 2) { GLOAD(kwb2, ch + 1); }
    const int buf = (ch + 1) & 1;
    const int cc = ch * 96 + c;
    float P[16];
#pragma unroll
    for (int m = 0; m < 16; ++m)
      P[m] = bf2f(Sbase[(long long)m * (TT * SW) + cc]) * rz[m];
    float hk0 = 0.f, hk1 = 0.f;
    float rt[16];
#pragma unroll
    for (int n = 0; n < 16; ++n) rt[n] = 0.f;
#pragma unroll
    for (int m = 0; m < 16; ++m) {
      hk0 = fmaf(P[m], bf2f(skw[buf][2 * m][c]), hk0);
      hk1 = fmaf(P[m], bf2f(skw[buf][2 * m + 1][c]), hk1);
      const float* MQ = &sMq[tj][m * 16];
#pragma unroll
      for (int n4 = 0; n4 < 4; ++n4) {
        f32x4 w = *(const f32x4*)(MQ + n4 * 4);
        rt[n4*4+0] = fmaf(P[m], w[0], rt[n4*4+0]);
        rt[n4*4+1] = fmaf(P[m], w[1], rt[n4*4+1]);
        rt[n4*4+2] = fmaf(P[m], w[2], rt[n4*4+2]);
        rt[n4*4+3] = fmaf(P[m], w[3], rt[n4*4+3]);
      }
    }
#pragma unroll
    for (int n = 0; n < 16; ++n) {
      float x = rt[n] + hk0 * bf2f(skw[buf][32 + 2 * n][c])
              + hk1 * bf2f(skw[buf][33 + 2 * n][c])
              + P[n] * bf2f(skw[buf][64 + n][c]);
      Sbase[(long long)n * (TT * SW) + cc] = f2bf(x);
    }
    if (ch < 2) DSWR(ch & 1);
    __syncthreads();
  }
}

// ---------- KC: PV band GEMM per (b,h,32-t tile) ----------
__global__ __launch_bounds__(256, 4)
void kc_pv(const ushort* __restrict__ S, const ushort* __restrict__ v8,
           float* __restrict__ out)
{
  const int tid = threadIdx.x;
  const int raw = blockIdx.x;                  // 1024 = 8*128
  const int job = (raw & 7) * 128 + (raw >> 3);
  const int b = job >> 9, h = (job >> 5) & 15, tt = job & 31;
  const int t0 = tt * 32;
  const int s0 = (t0 >= WIN) ? t0 - WIN : 0;
  const int lane = tid & 63, wv = tid >> 6;

  __shared__ ushort sPt[32 * 296];

  const long long prow0 = (((long long)(b * NH + h)) * TT + t0) * SW;
#pragma unroll
  for (int it = 0; it < 5; ++it) {
    int idx = tid + it * 256;
    if (idx < 32 * 36) {
      int r = idx / 36, sg = idx % 36;
      uint4 v = *(const uint4*)(S + prow0 + (long long)r * SW + sg * 8);
      *(uint4*)(&sPt[r * 296 + sg * 8]) = v;
    }
  }
  __syncthreads();

  const ushort* vbase = v8 + ((long long)(b * NH + h)) * (128 * DD * 8)
                           + ((long long)(s0 >> 3)) * (DD * 8);
  const int dcol = lane & 15, soct = lane >> 4;
  const int dt0 = wv * 2;
  f32x4 acc[2][2];
#pragma unroll
  for (int rt = 0; rt < 2; ++rt)
#pragma unroll
    for (int dd = 0; dd < 2; ++dd) acc[rt][dd] = (f32x4){0.f, 0.f, 0.f, 0.f};

#pragma unroll
  for (int ks = 0; ks < 9; ++ks) {
    s16x8 a0 = *(const s16x8*)(&sPt[(dcol) * 296 + ks * 32 + soct * 8]);
    s16x8 a1 = *(const s16x8*)(&sPt[(16 + dcol) * 296 + ks * 32 + soct * 8]);
#pragma unroll
    for (int dd = 0; dd < 2; ++dd) {
      s16x8 vb = *(const s16x8*)(vbase + (((long long)(ks * 4 + soct)) * DD + (dt0 + dd) * 16 + dcol) * 8);
      acc[0][dd] = __builtin_amdgcn_mfma_f32_16x16x32_bf16(a0, vb, acc[0][dd], 0, 0, 0);
      acc[1][dd] = __builtin_amdgcn_mfma_f32_16x16x32_bf16(a1, vb, acc[1][dd], 0, 0, 0);
    }
  }
  const int r0 = (lane >> 4) * 4;
#pragma unroll
  for (int rt = 0; rt < 2; ++rt)
#pragma unroll
    for (int dd = 0; dd < 2; ++dd)
#pragma unroll
      for (int j = 0; j < 4; ++j) {
        int trow = t0 + rt * 16 + r0 + j;
        out[(((long long)(b * TT + trow)) * NH + h) * DD + (dt0 + dd) * 16 + dcol] = acc[rt][dd][j];
      }
}

extern "C" void kernel_launch(void* const* d_in, const int* in_sizes, int n_in,
                              void* d_out, int out_size, void* d_ws, size_t ws_size,
                              hipStream_t stream) {
  const float* q        = (const float*)d_in[0];
  const float* k        = (const float*)d_in[1];
  const float* v        = (const float*)d_in[2];
  const float* w_pre    = (const float*)d_in[3];
  const float* w_post   = (const float*)d_in[4];
  const float* qw1_pre  = (const float*)d_in[5];
  const float* qw2_pre  = (const float*)d_in[6];
  const float* kw1_pre  = (const float*)d_in[7];
  const float* kw2_pre  = (const float*)d_in[8];
  const float* qw1_post = (const float*)d_in[9];
  const float* qw2_post = (const float*)d_in[10];
  const float* kw1_post = (const float*)d_in[11];
  const float* kw2_post = (const float*)d_in[12];
  const float* qdd_pre  = (const float*)d_in[13];
  const float* kdd_pre  = (const float*)d_in[14];
  const float* qdd_post = (const float*)d_in[15];
  const float* kdd_post = (const float*)d_in[16];
  float* out = (float*)d_out;

  // ws: qb8 8MB | kb8 8MB | v8 8MB | S 18MB | kwsT 640KB
  ushort* qb8  = (ushort*)d_ws;
  ushort* kb8  = (ushort*)((char*)d_ws + 8388608ll);
  ushort* v8   = (ushort*)((char*)d_ws + 16777216ll);
  ushort* S    = (ushort*)((char*)d_ws + 25165824ll);
  ushort* kwsT = (ushort*)((char*)d_ws + 44040192ll);

  prep_qk <<<512, 256, 0, stream>>>(q, qb8, SCALE);
  prep_qk <<<512, 256, 0, stream>>>(k, kb8, 1.0f);
  prep_v  <<<512, 256, 0, stream>>>(v, v8);
  prep_kws<<<64, 256, 0, stream>>>(kw1_pre, kw2_pre, kdd_pre,
                                   kw1_post, kw2_post, kdd_post, kwsT);
  ka_qk   <<<1024, 256, 0, stream>>>(qb8, kb8, S);
  kb_proj <<<1024, 192, 0, stream>>>(w_pre, w_post,
                                     qw1_pre, qw2_pre, qdd_pre,
                                     qw1_post, qw2_post, qdd_post,
                                     kwsT, S);
  kc_pv   <<<1024, 256, 0, stream>>>(S, v8, out);
}